// Round 6
// baseline (498.132 us; speedup 1.0000x reference)
//
#include <hip/hip_runtime.h>
#include <hip/hip_bf16.h>

#define NPTS    524288
#define NG      64
#define GSZ     64
#define VOX     (GSZ*GSZ*GSZ)       // 262144
#define NODES   64
#define TILE    64                  // points per block
#define NBLK    (NPTS / TILE)       // 8192
#define K0      192                 // padded K for layer-0 (164 -> 192)
#define SF      200                 // F row stride (bf16): 400B rows, 16B-aligned
#define NCELL   4096                // 16^3 Morton cells

typedef __attribute__((ext_vector_type(8))) short bf16x8;
typedef __attribute__((ext_vector_type(4))) float f32x4;

__device__ inline unsigned short f2bf(float f) {
    __hip_bfloat16 b = __float2bfloat16(f);
    union { __hip_bfloat16 h; unsigned short u; } cv; cv.h = b;
    return cv.u;
}
__device__ inline unsigned int pk2(float c0, float c1) {
    return (unsigned int)f2bf(c0) | ((unsigned int)f2bf(c1) << 16);
}
__device__ inline float bflo(unsigned int v) { return __uint_as_float(v << 16); }
__device__ inline float bfhi(unsigned int v) { return __uint_as_float(v & 0xffff0000u); }

__device__ inline int spread4(int v) {   // 4 bits -> bits 0,3,6,9
    return (v & 1) | ((v & 2) << 2) | ((v & 4) << 4) | ((v & 8) << 6);
}
__device__ inline int compact4(int v) {  // bits 0,3,6,9 -> 0..3
    return (v & 1) | ((v >> 2) & 2) | ((v >> 4) & 4) | ((v >> 6) & 8);
}
__device__ inline int cell_of(float px, float py, float pz) {
    int cx = min(max((int)((px + 1.0f) * 8.0f), 0), 15);
    int cy = min(max((int)((py + 1.0f) * 8.0f), 0), 15);
    int cz = min(max((int)((pz + 1.0f) * 8.0f), 0), 15);
    return spread4(cx) | (spread4(cy) << 1) | (spread4(cz) << 2);
}

// ---- P1: w_prep + hist zero (blocks 0..15) | cell-grid masks (blocks 16..1039) ----
// NOTE round-5 bug: must cover ALL 4096 cells -> 16 + NCELL/4 = 1040 blocks.
__global__ void prep_small(const float* __restrict__ W0, const float* __restrict__ W1,
                           const float* __restrict__ gscale, const float* __restrict__ gtrans,
                           unsigned short* __restrict__ w0t, unsigned short* __restrict__ w1t,
                           int* __restrict__ hist, uint2* __restrict__ masks) {
    int bid = blockIdx.x, tid = threadIdx.x;
    if (bid < 16) {
        int t = bid * 256 + tid;            // 0..4095
        hist[t] = 0;
        for (int i = t; i < NODES * K0; i += 4096) {
            int n = i / K0, k = i - n * K0;
            w0t[i] = (k < 164) ? f2bf(W0[k * NODES + n]) : (unsigned short)0;
        }
        for (int i = t; i < NODES * NODES; i += 4096) {
            int n = i >> 6, k = i & 63;
            w1t[i] = f2bf(W1[k * NODES + n]);
        }
    } else {
        // one wave per cell, lane = grid
        int cell = (bid - 16) * 4 + (tid >> 6);
        if (cell >= NCELL) return;
        int g = tid & 63;
        int cx = compact4(cell), cy = compact4(cell >> 1), cz = compact4(cell >> 2);
        float lo[3] = { -1.0f + cx * 0.125f, -1.0f + cy * 0.125f, -1.0f + cz * 0.125f };
        const float LOB = -1.0318f - 1e-4f, HIB = 1.0318f + 1e-4f;
        bool ok = true;
        #pragma unroll
        for (int a = 0; a < 3; ++a) {
            float s = gscale[g * 3 + a], t = gtrans[g * 3 + a];
            float cA = s * lo[a] + t, cB = s * (lo[a] + 0.125f) + t;
            float cmin = fminf(cA, cB), cmax = fmaxf(cA, cB);
            ok = ok && (cmax >= LOB) && (cmin <= HIB);
        }
        unsigned long long m = __ballot(ok);
        if (g == 0) masks[cell] = make_uint2((unsigned int)m, (unsigned int)(m >> 32));
    }
}

// ---- P2: histogram of cells ----
__global__ void sort_count(const float* __restrict__ x, int* __restrict__ hist) {
    int p = blockIdx.x * blockDim.x + threadIdx.x;
    int c = cell_of(x[p * 3 + 0], x[p * 3 + 1], x[p * 3 + 2]);
    atomicAdd(&hist[c], 1);
}

// ---- P3: exclusive scan of 4096 bins (1 block, 256 threads x 16 bins) ----
__global__ void sort_scan(const int* __restrict__ hist, int* __restrict__ offs) {
    __shared__ int partial[256];
    int t = threadIdx.x;
    int loc[16];
    int s = 0;
    #pragma unroll
    for (int i = 0; i < 16; ++i) { loc[i] = s; s += hist[t * 16 + i]; }
    partial[t] = s;
    __syncthreads();
    for (int d = 1; d < 256; d <<= 1) {
        int v = (t >= d) ? partial[t - d] : 0;
        __syncthreads();
        partial[t] += v;
        __syncthreads();
    }
    int base = partial[t] - s;
    #pragma unroll
    for (int i = 0; i < 16; ++i) offs[t * 16 + i] = base + loc[i];
}

// ---- P4: vox repack (blocks < 16384) | point scatter (rest) ----
__global__ void prep_big(const float* __restrict__ fg, uint4* __restrict__ vox4,
                         const float* __restrict__ x, int* __restrict__ offs,
                         float4* __restrict__ spts) {
    int bid = blockIdx.x, tid = threadIdx.x;
    if (bid < 16384) {
        int idx = bid * 256 + tid;          // NG*VOX/4
        int g = idx >> 16;
        int v = (idx & 65535) * 4;
        const float* base = fg + (size_t)g * (2 * VOX) + v;
        float4 a = *(const float4*)base;
        float4 b = *(const float4*)(base + VOX);
        vox4[idx] = make_uint4(pk2(a.x, b.x), pk2(a.y, b.y), pk2(a.z, b.z), pk2(a.w, b.w));
    } else {
        int p = (bid - 16384) * 256 + tid;
        float px = x[p * 3 + 0], py = x[p * 3 + 1], pz = x[p * 3 + 2];
        int c = cell_of(px, py, pz);
        int pos = atomicAdd(&offs[c], 1);
        spts[pos] = make_float4(px, py, pz, __int_as_float(p | (c << 19)));
    }
}

// ---- gather helpers: robust trilinear (correct for ANY point; OOB => exact zeros) ----
struct Pre {
    const unsigned int* r0; const unsigned int* r1;
    const unsigned int* r2; const unsigned int* r3;
    int x0o, x1o, dst;
    float wzy0, wzy1, wzy2, wzy3, wx0, wx1;
};

__device__ inline void prep_pair(int pt, int g, const float* xs,
                                 const float* gss, const float* gts,
                                 const unsigned int* __restrict__ vox, Pre& P) {
    float ix = (xs[pt * 3 + 0] * gss[g * 3 + 0] + gts[g * 3 + 0] + 1.0f) * 31.5f;
    float iy = (xs[pt * 3 + 1] * gss[g * 3 + 1] + gts[g * 3 + 1] + 1.0f) * 31.5f;
    float iz = (xs[pt * 3 + 2] * gss[g * 3 + 2] + gts[g * 3 + 2] + 1.0f) * 31.5f;
    float fx = floorf(ix), fy = floorf(iy), fz = floorf(iz);
    int x0 = (int)fx, y0 = (int)fy, z0 = (int)fz;
    float wx = ix - fx, wy = iy - fy, wz = iz - fz;
    // both-side validity per corner (robust to fully-OOB points)
    float wxa0 = ((unsigned)x0 < 64u) ? (1.0f - wx) : 0.0f;
    float wxa1 = ((unsigned)(x0 + 1) < 64u) ? wx : 0.0f;
    float wya0 = ((unsigned)y0 < 64u) ? (1.0f - wy) : 0.0f;
    float wya1 = ((unsigned)(y0 + 1) < 64u) ? wy : 0.0f;
    float wza0 = ((unsigned)z0 < 64u) ? (1.0f - wz) : 0.0f;
    float wza1 = ((unsigned)(z0 + 1) < 64u) ? wz : 0.0f;
    int xc0 = min(max(x0, 0), 63), xc1 = min(max(x0 + 1, 0), 63);
    int yc0 = min(max(y0, 0), 63), yc1 = min(max(y0 + 1, 0), 63);
    int zc0 = min(max(z0, 0), 63), zc1 = min(max(z0 + 1, 0), 63);
    const unsigned int* vg = vox + ((size_t)g << 18);
    P.r0 = vg + (((zc0 << 6) + yc0) << 6);
    P.r1 = vg + (((zc0 << 6) + yc1) << 6);
    P.r2 = vg + (((zc1 << 6) + yc0) << 6);
    P.r3 = vg + (((zc1 << 6) + yc1) << 6);
    P.wzy0 = wza0 * wya0; P.wzy1 = wza0 * wya1;
    P.wzy2 = wza1 * wya0; P.wzy3 = wza1 * wya1;
    P.x0o = xc0; P.x1o = xc1;
    P.wx0 = wxa0; P.wx1 = wxa1;
    P.dst = pt * SF + 36 + 2 * g;
}

__device__ inline void load8(const Pre& P, unsigned int* v) {
    v[0] = P.r0[P.x0o]; v[1] = P.r0[P.x1o];
    v[2] = P.r1[P.x0o]; v[3] = P.r1[P.x1o];
    v[4] = P.r2[P.x0o]; v[5] = P.r2[P.x1o];
    v[6] = P.r3[P.x0o]; v[7] = P.r3[P.x1o];
}

__device__ inline void math_pair(const Pre& P, const unsigned int* v, unsigned short* Fsh) {
    float f0 = P.wzy0 * (P.wx0 * bflo(v[0]) + P.wx1 * bflo(v[1]))
             + P.wzy1 * (P.wx0 * bflo(v[2]) + P.wx1 * bflo(v[3]))
             + P.wzy2 * (P.wx0 * bflo(v[4]) + P.wx1 * bflo(v[5]))
             + P.wzy3 * (P.wx0 * bflo(v[6]) + P.wx1 * bflo(v[7]));
    float f1 = P.wzy0 * (P.wx0 * bfhi(v[0]) + P.wx1 * bfhi(v[1]))
             + P.wzy1 * (P.wx0 * bfhi(v[2]) + P.wx1 * bfhi(v[3]))
             + P.wzy2 * (P.wx0 * bfhi(v[4]) + P.wx1 * bfhi(v[5]))
             + P.wzy3 * (P.wx0 * bfhi(v[6]) + P.wx1 * bfhi(v[7]));
    *(unsigned int*)&Fsh[P.dst] = pk2(f0, f1);
}

// ---- main fused kernel ----
__global__ void __launch_bounds__(256, 5)
amrsrn_main(const float4* __restrict__ spts,
            const float* __restrict__ gscale,
            const float* __restrict__ gtrans,
            const unsigned int* __restrict__ vox,
            const uint2* __restrict__ masks,
            const unsigned short* __restrict__ w0t,
            const unsigned short* __restrict__ w1t,
            const float* __restrict__ b0,
            const float* __restrict__ b1,
            const float* __restrict__ W2,
            const float* __restrict__ b2,
            float* __restrict__ out) {
    __shared__ unsigned short Fsh[TILE * SF];   // 25600 B
    __shared__ float xs[TILE * 3];
    __shared__ int   sraw[TILE];
    __shared__ float gss[NG * 3];
    __shared__ float gts[NG * 3];
    __shared__ unsigned int bm[2];
    __shared__ unsigned char glist[NG];

    const int tid = threadIdx.x;
    const int lane = tid & 63;
    // XCD swizzle: each XCD sweeps a contiguous Morton range
    const int cb = ((blockIdx.x & 7) << 10) | (blockIdx.x >> 3);
    const int base = cb * TILE;

    // ---- phase 0: zero F, stage points + tables ----
    for (int i = tid; i < TILE * SF / 8; i += 256) ((uint4*)Fsh)[i] = make_uint4(0, 0, 0, 0);
    if (tid < TILE) {
        float4 sp = spts[base + tid];
        xs[tid * 3 + 0] = sp.x; xs[tid * 3 + 1] = sp.y; xs[tid * 3 + 2] = sp.z;
        sraw[tid] = __float_as_int(sp.w);
    }
    if (tid < NG * 3) { gss[tid] = gscale[tid]; gts[tid] = gtrans[tid]; }
    if (tid < 2) bm[tid] = 0;
    __syncthreads();

    // ---- phase 1: PE (cols 0..35) + OR per-cell grid masks over the block's cell range ----
    {
        int pt = tid & 63;
        int grp = tid >> 6;
        #pragma unroll
        for (int t = 0; t < 9; ++t) {
            int tau = grp * 9 + t;
            int tt = (tau < 18) ? tau : tau - 18;
            int l = tt / 3, d = tt - l * 3;
            float ang = xs[pt * 3 + d] * (3.14159265358979323846f * (float)(1 << l));
            float val = (tau < 18) ? __sinf(ang) : __cosf(ang);
            Fsh[pt * SF + tau] = f2bf(val);
        }
        unsigned int c0 = ((unsigned int)sraw[0]) >> 19;
        unsigned int c1 = ((unsigned int)sraw[TILE - 1]) >> 19;
        for (unsigned int c = c0 + tid; c <= c1; c += 256) {
            uint2 m = masks[c];
            atomicOr(&bm[0], m.x);
            atomicOr(&bm[1], m.y);
        }
    }
    __syncthreads();

    unsigned long long mask = (unsigned long long)bm[0] | ((unsigned long long)bm[1] << 32);
    int ng = __popcll(mask);
    if (tid < NG && ((mask >> tid) & 1ull))
        glist[__popcll(mask & ((1ull << tid) - 1ull))] = (unsigned char)tid;
    __syncthreads();

    // ---- phase 2: gather. item i: pt = i&63, grid = glist[i>>6] (one grid per wave) ----
    {
        int n64 = ng << 6;
        for (int i = tid; i < n64; i += 512) {
            int j = (i + 256 < n64) ? i + 256 : i;
            Pre A, B;
            prep_pair(i & 63, glist[i >> 6], xs, gss, gts, vox, A);
            prep_pair(j & 63, glist[j >> 6], xs, gss, gts, vox, B);
            unsigned int va[8], vb[8];
            load8(A, va);
            load8(B, vb);
            math_pair(A, va, Fsh);
            math_pair(B, vb, Fsh);
        }
    }
    __syncthreads();

    // ---- phase 3: MFMA MLP. wave w owns pts [16w, 16w+16) ----
    const int wv = tid >> 6;
    const int ptb = wv * 16;
    const int row = lane & 15;
    const int quad = lane >> 4;
    const int koff = quad * 8;

    f32x4 acc0[4] = {{0,0,0,0},{0,0,0,0},{0,0,0,0},{0,0,0,0}};
    #pragma unroll
    for (int ks = 0; ks < 6; ++ks) {
        bf16x8 a = *(const bf16x8*)&Fsh[(ptb + row) * SF + ks * 32 + koff];
        #pragma unroll
        for (int nt = 0; nt < 4; ++nt) {
            bf16x8 b = *(const bf16x8*)&w0t[(nt * 16 + row) * K0 + ks * 32 + koff];
            acc0[nt] = __builtin_amdgcn_mfma_f32_16x16x32_bf16(a, b, acc0[nt], 0, 0, 0);
        }
    }
    #pragma unroll
    for (int nt = 0; nt < 4; ++nt) {
        int node = nt * 16 + row;
        float bb = b0[node];
        #pragma unroll
        for (int r = 0; r < 4; ++r) {
            float h = acc0[nt][r] + bb;
            float s = __sinf(h);
            h = 0.5f * h + s * s;
            Fsh[(ptb + quad * 4 + r) * SF + node] = f2bf(h);
        }
    }

    f32x4 acc1[4] = {{0,0,0,0},{0,0,0,0},{0,0,0,0},{0,0,0,0}};
    #pragma unroll
    for (int ks = 0; ks < 2; ++ks) {
        bf16x8 a = *(const bf16x8*)&Fsh[(ptb + row) * SF + ks * 32 + koff];
        #pragma unroll
        for (int nt = 0; nt < 4; ++nt) {
            bf16x8 b = *(const bf16x8*)&w1t[(nt * 16 + row) * NODES + ks * 32 + koff];
            acc1[nt] = __builtin_amdgcn_mfma_f32_16x16x32_bf16(a, b, acc1[nt], 0, 0, 0);
        }
    }
    float part[4] = {0.f, 0.f, 0.f, 0.f};
    #pragma unroll
    for (int nt = 0; nt < 4; ++nt) {
        int node = nt * 16 + row;
        float b1v = b1[node];
        float w2v = W2[node];
        #pragma unroll
        for (int r = 0; r < 4; ++r) {
            float h = acc1[nt][r] + b1v;
            float s = __sinf(h);
            h = 0.5f * h + s * s;
            part[r] += h * w2v;
        }
    }
    #pragma unroll
    for (int m = 1; m < 16; m <<= 1) {
        #pragma unroll
        for (int r = 0; r < 4; ++r) part[r] += __shfl_xor(part[r], m);
    }
    if (row == 0) {
        float b2v = b2[0];
        #pragma unroll
        for (int r = 0; r < 4; ++r) {
            int pt = ptb + quad * 4 + r;
            out[sraw[pt] & 0x7FFFF] = part[r] + b2v;
        }
    }
}

// ---- fallback (no workspace): direct fp32 kernel ----
__global__ void amrsrn_fallback(const float* __restrict__ x,
                                const float* __restrict__ gscale,
                                const float* __restrict__ gtrans,
                                const float* __restrict__ fg,
                                const float* __restrict__ W0,
                                const float* __restrict__ b0,
                                const float* __restrict__ W1,
                                const float* __restrict__ b1,
                                const float* __restrict__ W2,
                                const float* __restrict__ b2,
                                float* __restrict__ out) {
    int p = blockIdx.x * blockDim.x + threadIdx.x;
    float px = x[p*3+0], py = x[p*3+1], pz = x[p*3+2];
    float h0[NODES];
    #pragma unroll
    for (int j = 0; j < NODES; ++j) h0[j] = b0[j];
    #pragma unroll
    for (int l = 0; l < 6; ++l) {
        float freq = 3.14159265358979323846f * (float)(1 << l);
        #pragma unroll
        for (int d = 0; d < 3; ++d) {
            float v = (d == 0 ? px : (d == 1 ? py : pz)) * freq;
            float s = __sinf(v), c = __cosf(v);
            const float* wrs = W0 + (l*3 + d) * NODES;
            const float* wrc = W0 + (18 + l*3 + d) * NODES;
            #pragma unroll
            for (int j = 0; j < NODES; ++j) h0[j] += s * wrs[j] + c * wrc[j];
        }
    }
    for (int g = 0; g < NG; ++g) {
        float ix = (px * gscale[g*3+0] + gtrans[g*3+0] + 1.0f) * 31.5f;
        float iy = (py * gscale[g*3+1] + gtrans[g*3+1] + 1.0f) * 31.5f;
        float iz = (pz * gscale[g*3+2] + gtrans[g*3+2] + 1.0f) * 31.5f;
        float fxf = floorf(ix), fyf = floorf(iy), fzf = floorf(iz);
        int x0 = (int)fxf, y0 = (int)fyf, z0 = (int)fzf;
        float wx = ix - fxf, wy = iy - fyf, wz = iz - fzf;
        bool any = (x0 >= -1 && x0 < GSZ) && (y0 >= -1 && y0 < GSZ) && (z0 >= -1 && z0 < GSZ);
        if (any) {
            float f0 = 0.f, f1 = 0.f;
            #pragma unroll
            for (int dz = 0; dz < 2; ++dz) {
                int zi = z0 + dz; bool vz = ((unsigned)zi < (unsigned)GSZ);
                int zc = min(max(zi, 0), GSZ - 1);
                float wzf = dz ? wz : 1.f - wz;
                #pragma unroll
                for (int dy = 0; dy < 2; ++dy) {
                    int yi = y0 + dy; bool vy = ((unsigned)yi < (unsigned)GSZ);
                    int yc = min(max(yi, 0), GSZ - 1);
                    float wyf = dy ? wy : 1.f - wy;
                    int rowoff = (zc * GSZ + yc) * GSZ;
                    #pragma unroll
                    for (int dx = 0; dx < 2; ++dx) {
                        int xi = x0 + dx; bool vx = ((unsigned)xi < (unsigned)GSZ);
                        int xc = min(max(xi, 0), GSZ - 1);
                        float w = wzf * wyf * (dx ? wx : 1.f - wx);
                        w = (vz && vy && vx) ? w : 0.f;
                        const float* gp = fg + ((size_t)g << 19);
                        f0 += w * gp[rowoff + xc];
                        f1 += w * gp[VOX + rowoff + xc];
                    }
                }
            }
            const float* wr = W0 + (36 + 2*g) * NODES;
            #pragma unroll
            for (int j = 0; j < NODES; ++j) h0[j] += f0 * wr[j] + f1 * wr[NODES + j];
        }
    }
    #pragma unroll
    for (int j = 0; j < NODES; ++j) { float s = __sinf(h0[j]); h0[j] = 0.5f * h0[j] + s * s; }
    float out_acc = b2[0];
    #pragma unroll
    for (int half = 0; half < 2; ++half) {
        float h1[32];
        #pragma unroll
        for (int j = 0; j < 32; ++j) h1[j] = b1[half*32 + j];
        #pragma unroll
        for (int i = 0; i < NODES; ++i) {
            float a = h0[i];
            const float* w1r = W1 + i * NODES + half*32;
            #pragma unroll
            for (int j = 0; j < 32; ++j) h1[j] += a * w1r[j];
        }
        #pragma unroll
        for (int j = 0; j < 32; ++j) { float s = __sinf(h1[j]); out_acc += (0.5f * h1[j] + s * s) * W2[half*32 + j]; }
    }
    out[p] = out_acc;
}

extern "C" void kernel_launch(void* const* d_in, const int* in_sizes, int n_in,
                              void* d_out, int out_size, void* d_ws, size_t ws_size,
                              hipStream_t stream) {
    const float* x      = (const float*)d_in[0];
    const float* gscale = (const float*)d_in[1];
    const float* gtrans = (const float*)d_in[2];
    const float* fg     = (const float*)d_in[3];
    const float* W0     = (const float*)d_in[4];
    const float* b0     = (const float*)d_in[5];
    const float* W1     = (const float*)d_in[6];
    const float* b1     = (const float*)d_in[7];
    const float* W2     = (const float*)d_in[8];
    const float* b2     = (const float*)d_in[9];
    float* out = (float*)d_out;

    // workspace layout:
    //   [0,      24576)  w0t
    //   [24576,  32768)  w1t
    //   [32768,  49152)  hist (4096 int)
    //   [49152,  65536)  offs (4096 int)
    //   [65536,  98304)  masks (4096 uint2)
    //   [1M,     9M)     spts (524288 float4)
    //   [9M,     73M)    vox (packed bf16x2)
    char* wsp = (char*)d_ws;
    unsigned short* w0t = (unsigned short*)wsp;
    unsigned short* w1t = (unsigned short*)(wsp + 24576);
    int* hist           = (int*)(wsp + 32768);
    int* offs           = (int*)(wsp + 49152);
    uint2* masks        = (uint2*)(wsp + 65536);
    float4* spts        = (float4*)(wsp + (1 << 20));
    unsigned int* vox   = (unsigned int*)(wsp + (9 << 20));
    const size_t ws_needed = (size_t)(9 << 20) + (size_t)NG * VOX * 4;

    if (ws_size >= ws_needed) {
        prep_small<<<16 + NCELL / 4, 256, 0, stream>>>(W0, W1, gscale, gtrans, w0t, w1t, hist, masks);
        sort_count<<<NPTS / 256, 256, 0, stream>>>(x, hist);
        sort_scan<<<1, 256, 0, stream>>>(hist, offs);
        prep_big<<<16384 + NPTS / 256, 256, 0, stream>>>(fg, (uint4*)vox, x, offs, spts);
        amrsrn_main<<<NBLK, 256, 0, stream>>>(spts, gscale, gtrans, vox, masks,
                                              w0t, w1t, b0, b1, W2, b2, out);
    } else {
        amrsrn_fallback<<<NPTS / 256, 256, 0, stream>>>(
            x, gscale, gtrans, fg, W0, b0, W1, b1, W2, b2, out);
    }
}

// Round 7
// 483.695 us; speedup vs baseline: 1.0298x; 1.0298x over previous
//
#include <hip/hip_runtime.h>
#include <hip/hip_bf16.h>

#define NPTS    524288
#define NG      64
#define GSZ     64
#define VOX     (GSZ*GSZ*GSZ)       // 262144
#define NODES   64
#define TILE    64                  // points per block
#define NBLK    (NPTS / TILE)       // 8192
#define K0      192                 // padded K for layer-0 (164 -> 192)
#define SF      200                 // F row stride (bf16): 400B rows, 16B-aligned
#define NCELL   4096                // 16^3 Morton cells
#define WLCAP   1792                // worklist cap (3.5 KB); overflow gathered inline

typedef __attribute__((ext_vector_type(8))) short bf16x8;
typedef __attribute__((ext_vector_type(4))) float f32x4;

__device__ inline unsigned short f2bf(float f) {
    __hip_bfloat16 b = __float2bfloat16(f);
    union { __hip_bfloat16 h; unsigned short u; } cv; cv.h = b;
    return cv.u;
}
__device__ inline unsigned int pk2(float c0, float c1) {
    return (unsigned int)f2bf(c0) | ((unsigned int)f2bf(c1) << 16);
}
__device__ inline float bflo(unsigned int v) { return __uint_as_float(v << 16); }
__device__ inline float bfhi(unsigned int v) { return __uint_as_float(v & 0xffff0000u); }

__device__ inline int spread4(int v) {   // 4 bits -> bits 0,3,6,9
    return (v & 1) | ((v & 2) << 2) | ((v & 4) << 4) | ((v & 8) << 6);
}
__device__ inline int compact4(int v) {  // bits 0,3,6,9 -> 0..3
    return (v & 1) | ((v >> 2) & 2) | ((v >> 4) & 4) | ((v >> 6) & 8);
}
__device__ inline int cell_of(float px, float py, float pz) {
    int cx = min(max((int)((px + 1.0f) * 8.0f), 0), 15);
    int cy = min(max((int)((py + 1.0f) * 8.0f), 0), 15);
    int cz = min(max((int)((pz + 1.0f) * 8.0f), 0), 15);
    return spread4(cx) | (spread4(cy) << 1) | (spread4(cz) << 2);
}

// ---- P1: weights (blocks 0..15) | cell-grid masks (16..1039) | cell histogram (1040..) ----
// hist must be zeroed beforehand (hipMemsetAsync).
__global__ void prep_small(const float* __restrict__ W0, const float* __restrict__ W1,
                           const float* __restrict__ gscale, const float* __restrict__ gtrans,
                           const float* __restrict__ x,
                           unsigned short* __restrict__ w0t, unsigned short* __restrict__ w1t,
                           int* __restrict__ hist, uint2* __restrict__ masks) {
    int bid = blockIdx.x, tid = threadIdx.x;
    if (bid < 16) {
        int t = bid * 256 + tid;
        for (int i = t; i < NODES * K0; i += 4096) {
            int n = i / K0, k = i - n * K0;
            w0t[i] = (k < 164) ? f2bf(W0[k * NODES + n]) : (unsigned short)0;
        }
        for (int i = t; i < NODES * NODES; i += 4096) {
            int n = i >> 6, k = i & 63;
            w1t[i] = f2bf(W1[k * NODES + n]);
        }
    } else if (bid < 16 + NCELL / 4) {
        int cell = (bid - 16) * 4 + (tid >> 6);
        int g = tid & 63;
        int cx = compact4(cell), cy = compact4(cell >> 1), cz = compact4(cell >> 2);
        float lo[3] = { -1.0f + cx * 0.125f, -1.0f + cy * 0.125f, -1.0f + cz * 0.125f };
        const float LOB = -1.0318f - 1e-4f, HIB = 1.0318f + 1e-4f;
        bool ok = true;
        #pragma unroll
        for (int a = 0; a < 3; ++a) {
            float s = gscale[g * 3 + a], t = gtrans[g * 3 + a];
            float cA = s * lo[a] + t, cB = s * (lo[a] + 0.125f) + t;
            float cmin = fminf(cA, cB), cmax = fmaxf(cA, cB);
            ok = ok && (cmax >= LOB) && (cmin <= HIB);
        }
        unsigned long long m = __ballot(ok);
        if (g == 0) masks[cell] = make_uint2((unsigned int)m, (unsigned int)(m >> 32));
    } else {
        int p = (bid - 16 - NCELL / 4) * 256 + tid;
        int c = cell_of(x[p * 3 + 0], x[p * 3 + 1], x[p * 3 + 2]);
        atomicAdd(&hist[c], 1);
    }
}

// ---- P2: exclusive scan of 4096 bins (1 block, 256 threads x 16 bins) ----
__global__ void sort_scan(const int* __restrict__ hist, int* __restrict__ offs) {
    __shared__ int partial[256];
    int t = threadIdx.x;
    int loc[16];
    int s = 0;
    #pragma unroll
    for (int i = 0; i < 16; ++i) { loc[i] = s; s += hist[t * 16 + i]; }
    partial[t] = s;
    __syncthreads();
    for (int d = 1; d < 256; d <<= 1) {
        int v = (t >= d) ? partial[t - d] : 0;
        __syncthreads();
        partial[t] += v;
        __syncthreads();
    }
    int base = partial[t] - s;
    #pragma unroll
    for (int i = 0; i < 16; ++i) offs[t * 16 + i] = base + loc[i];
}

// ---- P3: vox repack (blocks < 16384) | point scatter (rest) ----
__global__ void prep_big(const float* __restrict__ fg, uint4* __restrict__ vox4,
                         const float* __restrict__ x, int* __restrict__ offs,
                         float4* __restrict__ spts) {
    int bid = blockIdx.x, tid = threadIdx.x;
    if (bid < 16384) {
        int idx = bid * 256 + tid;          // NG*VOX/4
        int g = idx >> 16;
        int v = (idx & 65535) * 4;
        const float* base = fg + (size_t)g * (2 * VOX) + v;
        float4 a = *(const float4*)base;
        float4 b = *(const float4*)(base + VOX);
        vox4[idx] = make_uint4(pk2(a.x, b.x), pk2(a.y, b.y), pk2(a.z, b.z), pk2(a.w, b.w));
    } else {
        int p = (bid - 16384) * 256 + tid;
        float px = x[p * 3 + 0], py = x[p * 3 + 1], pz = x[p * 3 + 2];
        int c = cell_of(px, py, pz);
        int pos = atomicAdd(&offs[c], 1);
        spts[pos] = make_float4(px, py, pz, __int_as_float(p | (c << 19)));
    }
}

// ---- gather helpers: robust trilinear (correct for ANY point; OOB => exact zeros) ----
struct Pre {
    const unsigned int* r0; const unsigned int* r1;
    const unsigned int* r2; const unsigned int* r3;
    int x0o, x1o, dst;
    float wzy0, wzy1, wzy2, wzy3, wx0, wx1;
};

__device__ inline void prep_pair(int pt, int g, const float* xs,
                                 const float* gss, const float* gts,
                                 const unsigned int* __restrict__ vox, Pre& P) {
    float ix = (xs[pt * 3 + 0] * gss[g * 3 + 0] + gts[g * 3 + 0] + 1.0f) * 31.5f;
    float iy = (xs[pt * 3 + 1] * gss[g * 3 + 1] + gts[g * 3 + 1] + 1.0f) * 31.5f;
    float iz = (xs[pt * 3 + 2] * gss[g * 3 + 2] + gts[g * 3 + 2] + 1.0f) * 31.5f;
    float fx = floorf(ix), fy = floorf(iy), fz = floorf(iz);
    int x0 = (int)fx, y0 = (int)fy, z0 = (int)fz;
    float wx = ix - fx, wy = iy - fy, wz = iz - fz;
    float wxa0 = ((unsigned)x0 < 64u) ? (1.0f - wx) : 0.0f;
    float wxa1 = ((unsigned)(x0 + 1) < 64u) ? wx : 0.0f;
    float wya0 = ((unsigned)y0 < 64u) ? (1.0f - wy) : 0.0f;
    float wya1 = ((unsigned)(y0 + 1) < 64u) ? wy : 0.0f;
    float wza0 = ((unsigned)z0 < 64u) ? (1.0f - wz) : 0.0f;
    float wza1 = ((unsigned)(z0 + 1) < 64u) ? wz : 0.0f;
    int xc0 = min(max(x0, 0), 63), xc1 = min(max(x0 + 1, 0), 63);
    int yc0 = min(max(y0, 0), 63), yc1 = min(max(y0 + 1, 0), 63);
    int zc0 = min(max(z0, 0), 63), zc1 = min(max(z0 + 1, 0), 63);
    const unsigned int* vg = vox + ((size_t)g << 18);
    P.r0 = vg + (((zc0 << 6) + yc0) << 6);
    P.r1 = vg + (((zc0 << 6) + yc1) << 6);
    P.r2 = vg + (((zc1 << 6) + yc0) << 6);
    P.r3 = vg + (((zc1 << 6) + yc1) << 6);
    P.wzy0 = wza0 * wya0; P.wzy1 = wza0 * wya1;
    P.wzy2 = wza1 * wya0; P.wzy3 = wza1 * wya1;
    P.x0o = xc0; P.x1o = xc1;
    P.wx0 = wxa0; P.wx1 = wxa1;
    P.dst = pt * SF + 36 + 2 * g;
}

__device__ inline void load8(const Pre& P, unsigned int* v) {
    v[0] = P.r0[P.x0o]; v[1] = P.r0[P.x1o];
    v[2] = P.r1[P.x0o]; v[3] = P.r1[P.x1o];
    v[4] = P.r2[P.x0o]; v[5] = P.r2[P.x1o];
    v[6] = P.r3[P.x0o]; v[7] = P.r3[P.x1o];
}

__device__ inline void math_pair(const Pre& P, const unsigned int* v, unsigned short* Fsh) {
    float f0 = P.wzy0 * (P.wx0 * bflo(v[0]) + P.wx1 * bflo(v[1]))
             + P.wzy1 * (P.wx0 * bflo(v[2]) + P.wx1 * bflo(v[3]))
             + P.wzy2 * (P.wx0 * bflo(v[4]) + P.wx1 * bflo(v[5]))
             + P.wzy3 * (P.wx0 * bflo(v[6]) + P.wx1 * bflo(v[7]));
    float f1 = P.wzy0 * (P.wx0 * bfhi(v[0]) + P.wx1 * bfhi(v[1]))
             + P.wzy1 * (P.wx0 * bfhi(v[2]) + P.wx1 * bfhi(v[3]))
             + P.wzy2 * (P.wx0 * bfhi(v[4]) + P.wx1 * bfhi(v[5]))
             + P.wzy3 * (P.wx0 * bfhi(v[6]) + P.wx1 * bfhi(v[7]));
    *(unsigned int*)&Fsh[P.dst] = pk2(f0, f1);
}

// ---- main fused kernel ----
__global__ void __launch_bounds__(256, 5)
amrsrn_main(const float4* __restrict__ spts,
            const float* __restrict__ gscale,
            const float* __restrict__ gtrans,
            const unsigned int* __restrict__ vox,
            const uint2* __restrict__ masks,
            const unsigned short* __restrict__ w0t,
            const unsigned short* __restrict__ w1t,
            const float* __restrict__ b0,
            const float* __restrict__ b1,
            const float* __restrict__ W2,
            const float* __restrict__ b2,
            float* __restrict__ out) {
    __shared__ unsigned short Fsh[TILE * SF];   // 25600 B
    __shared__ unsigned short wl[WLCAP];        // 3584 B
    __shared__ float xs[TILE * 3];
    __shared__ int   sraw[TILE];
    __shared__ float gss[NG * 3];
    __shared__ float gts[NG * 3];
    __shared__ unsigned int bm[2];
    __shared__ unsigned char glist[NG];
    __shared__ int wl_cnt;

    const int tid = threadIdx.x;
    const int lane = tid & 63;
    const int wv = tid >> 6;
    // XCD swizzle: each XCD sweeps a contiguous Morton range
    const int cb = ((blockIdx.x & 7) << 10) | (blockIdx.x >> 3);
    const int base = cb * TILE;

    // ---- phase 0: zero F, stage points + tables ----
    for (int i = tid; i < TILE * SF / 8; i += 256) ((uint4*)Fsh)[i] = make_uint4(0, 0, 0, 0);
    if (tid < TILE) {
        float4 sp = spts[base + tid];
        xs[tid * 3 + 0] = sp.x; xs[tid * 3 + 1] = sp.y; xs[tid * 3 + 2] = sp.z;
        sraw[tid] = __float_as_int(sp.w);
    }
    if (tid < NG * 3) { gss[tid] = gscale[tid]; gts[tid] = gtrans[tid]; }
    if (tid < 2) bm[tid] = 0;
    if (tid == 0) wl_cnt = 0;
    __syncthreads();

    // ---- phase 1: PE (cols 0..35) + union of per-cell grid masks ----
    {
        int pt = tid & 63;
        int grp = tid >> 6;
        #pragma unroll
        for (int t = 0; t < 9; ++t) {
            int tau = grp * 9 + t;
            int tt = (tau < 18) ? tau : tau - 18;
            int l = tt / 3, d = tt - l * 3;
            float ang = xs[pt * 3 + d] * (3.14159265358979323846f * (float)(1 << l));
            float val = (tau < 18) ? __sinf(ang) : __cosf(ang);
            Fsh[pt * SF + tau] = f2bf(val);
        }
        unsigned int c0 = ((unsigned int)sraw[0]) >> 19;
        unsigned int c1 = ((unsigned int)sraw[TILE - 1]) >> 19;
        for (unsigned int c = c0 + tid; c <= c1; c += 256) {
            uint2 m = masks[c];
            atomicOr(&bm[0], m.x);
            atomicOr(&bm[1], m.y);
        }
    }
    __syncthreads();

    unsigned long long mask = (unsigned long long)bm[0] | ((unsigned long long)bm[1] << 32);
    int ng = __popcll(mask);
    if (tid < NG && ((mask >> tid) & 1ull))
        glist[__popcll(mask & ((1ull << tid) - 1ull))] = (unsigned char)tid;
    __syncthreads();

    // ---- phase 1b: exact per-point scan over union grids only -> worklist ----
    {
        int pt = lane;
        float px = xs[pt * 3 + 0], py = xs[pt * 3 + 1], pz = xs[pt * 3 + 2];
        for (int k = wv; k < ng; k += 4) {
            int g = glist[k];
            float ix = (px * gss[g * 3 + 0] + gts[g * 3 + 0] + 1.0f) * 31.5f;
            float iy = (py * gss[g * 3 + 1] + gts[g * 3 + 1] + 1.0f) * 31.5f;
            float iz = (pz * gss[g * 3 + 2] + gts[g * 3 + 2] + 1.0f) * 31.5f;
            bool valid = (ix >= -1.0f) & (ix < 64.0f)
                       & (iy >= -1.0f) & (iy < 64.0f)
                       & (iz >= -1.0f) & (iz < 64.0f);
            unsigned long long m = __ballot(valid);
            if (m) {
                int b = 0;
                if (lane == 0) b = atomicAdd(&wl_cnt, __popcll(m));
                b = __shfl(b, 0);
                if (valid) {
                    int slot = b + __popcll(m & ((1ull << lane) - 1ull));
                    if (slot < WLCAP) {
                        wl[slot] = (unsigned short)((g << 6) | pt);
                    } else {
                        Pre P; unsigned int v[8];
                        prep_pair(pt, g, xs, gss, gts, vox, P);
                        load8(P, v);
                        math_pair(P, v, Fsh);
                    }
                }
            }
        }
    }
    __syncthreads();

    // ---- phase 2: gather valid pairs (grouped by grid, Morton-adjacent pts) ----
    {
        int n = min(wl_cnt, WLCAP);
        for (int i = tid; i < n; i += 512) {
            int j = (i + 256 < n) ? i + 256 : i;
            int ea = wl[i], eb = wl[j];
            Pre A, B;
            prep_pair(ea & 63, ea >> 6, xs, gss, gts, vox, A);
            prep_pair(eb & 63, eb >> 6, xs, gss, gts, vox, B);
            unsigned int va[8], vb[8];
            load8(A, va);
            load8(B, vb);
            math_pair(A, va, Fsh);
            math_pair(B, vb, Fsh);
        }
    }
    __syncthreads();

    // ---- phase 3: MFMA MLP. wave w owns pts [16w, 16w+16) ----
    const int ptb = wv * 16;
    const int row = lane & 15;
    const int quad = lane >> 4;
    const int koff = quad * 8;

    f32x4 acc0[4] = {{0,0,0,0},{0,0,0,0},{0,0,0,0},{0,0,0,0}};
    #pragma unroll
    for (int ks = 0; ks < 6; ++ks) {
        bf16x8 a = *(const bf16x8*)&Fsh[(ptb + row) * SF + ks * 32 + koff];
        #pragma unroll
        for (int nt = 0; nt < 4; ++nt) {
            bf16x8 b = *(const bf16x8*)&w0t[(nt * 16 + row) * K0 + ks * 32 + koff];
            acc0[nt] = __builtin_amdgcn_mfma_f32_16x16x32_bf16(a, b, acc0[nt], 0, 0, 0);
        }
    }
    #pragma unroll
    for (int nt = 0; nt < 4; ++nt) {
        int node = nt * 16 + row;
        float bb = b0[node];
        #pragma unroll
        for (int r = 0; r < 4; ++r) {
            float h = acc0[nt][r] + bb;
            float s = __sinf(h);
            h = 0.5f * h + s * s;
            Fsh[(ptb + quad * 4 + r) * SF + node] = f2bf(h);
        }
    }

    f32x4 acc1[4] = {{0,0,0,0},{0,0,0,0},{0,0,0,0},{0,0,0,0}};
    #pragma unroll
    for (int ks = 0; ks < 2; ++ks) {
        bf16x8 a = *(const bf16x8*)&Fsh[(ptb + row) * SF + ks * 32 + koff];
        #pragma unroll
        for (int nt = 0; nt < 4; ++nt) {
            bf16x8 b = *(const bf16x8*)&w1t[(nt * 16 + row) * NODES + ks * 32 + koff];
            acc1[nt] = __builtin_amdgcn_mfma_f32_16x16x32_bf16(a, b, acc1[nt], 0, 0, 0);
        }
    }
    float part[4] = {0.f, 0.f, 0.f, 0.f};
    #pragma unroll
    for (int nt = 0; nt < 4; ++nt) {
        int node = nt * 16 + row;
        float b1v = b1[node];
        float w2v = W2[node];
        #pragma unroll
        for (int r = 0; r < 4; ++r) {
            float h = acc1[nt][r] + b1v;
            float s = __sinf(h);
            h = 0.5f * h + s * s;
            part[r] += h * w2v;
        }
    }
    #pragma unroll
    for (int m = 1; m < 16; m <<= 1) {
        #pragma unroll
        for (int r = 0; r < 4; ++r) part[r] += __shfl_xor(part[r], m);
    }
    if (row == 0) {
        float b2v = b2[0];
        #pragma unroll
        for (int r = 0; r < 4; ++r) {
            int pt = ptb + quad * 4 + r;
            out[sraw[pt] & 0x7FFFF] = part[r] + b2v;
        }
    }
}

// ---- fallback (no workspace): direct fp32 kernel ----
__global__ void amrsrn_fallback(const float* __restrict__ x,
                                const float* __restrict__ gscale,
                                const float* __restrict__ gtrans,
                                const float* __restrict__ fg,
                                const float* __restrict__ W0,
                                const float* __restrict__ b0,
                                const float* __restrict__ W1,
                                const float* __restrict__ b1,
                                const float* __restrict__ W2,
                                const float* __restrict__ b2,
                                float* __restrict__ out) {
    int p = blockIdx.x * blockDim.x + threadIdx.x;
    float px = x[p*3+0], py = x[p*3+1], pz = x[p*3+2];
    float h0[NODES];
    #pragma unroll
    for (int j = 0; j < NODES; ++j) h0[j] = b0[j];
    #pragma unroll
    for (int l = 0; l < 6; ++l) {
        float freq = 3.14159265358979323846f * (float)(1 << l);
        #pragma unroll
        for (int d = 0; d < 3; ++d) {
            float v = (d == 0 ? px : (d == 1 ? py : pz)) * freq;
            float s = __sinf(v), c = __cosf(v);
            const float* wrs = W0 + (l*3 + d) * NODES;
            const float* wrc = W0 + (18 + l*3 + d) * NODES;
            #pragma unroll
            for (int j = 0; j < NODES; ++j) h0[j] += s * wrs[j] + c * wrc[j];
        }
    }
    for (int g = 0; g < NG; ++g) {
        float ix = (px * gscale[g*3+0] + gtrans[g*3+0] + 1.0f) * 31.5f;
        float iy = (py * gscale[g*3+1] + gtrans[g*3+1] + 1.0f) * 31.5f;
        float iz = (pz * gscale[g*3+2] + gtrans[g*3+2] + 1.0f) * 31.5f;
        float fxf = floorf(ix), fyf = floorf(iy), fzf = floorf(iz);
        int x0 = (int)fxf, y0 = (int)fyf, z0 = (int)fzf;
        float wx = ix - fxf, wy = iy - fyf, wz = iz - fzf;
        bool any = (x0 >= -1 && x0 < GSZ) && (y0 >= -1 && y0 < GSZ) && (z0 >= -1 && z0 < GSZ);
        if (any) {
            float f0 = 0.f, f1 = 0.f;
            #pragma unroll
            for (int dz = 0; dz < 2; ++dz) {
                int zi = z0 + dz; bool vz = ((unsigned)zi < (unsigned)GSZ);
                int zc = min(max(zi, 0), GSZ - 1);
                float wzf = dz ? wz : 1.f - wz;
                #pragma unroll
                for (int dy = 0; dy < 2; ++dy) {
                    int yi = y0 + dy; bool vy = ((unsigned)yi < (unsigned)GSZ);
                    int yc = min(max(yi, 0), GSZ - 1);
                    float wyf = dy ? wy : 1.f - wy;
                    int rowoff = (zc * GSZ + yc) * GSZ;
                    #pragma unroll
                    for (int dx = 0; dx < 2; ++dx) {
                        int xi = x0 + dx; bool vx = ((unsigned)xi < (unsigned)GSZ);
                        int xc = min(max(xi, 0), GSZ - 1);
                        float w = wzf * wyf * (dx ? wx : 1.f - wx);
                        w = (vz && vy && vx) ? w : 0.f;
                        const float* gp = fg + ((size_t)g << 19);
                        f0 += w * gp[rowoff + xc];
                        f1 += w * gp[VOX + rowoff + xc];
                    }
                }
            }
            const float* wr = W0 + (36 + 2*g) * NODES;
            #pragma unroll
            for (int j = 0; j < NODES; ++j) h0[j] += f0 * wr[j] + f1 * wr[NODES + j];
        }
    }
    #pragma unroll
    for (int j = 0; j < NODES; ++j) { float s = __sinf(h0[j]); h0[j] = 0.5f * h0[j] + s * s; }
    float out_acc = b2[0];
    #pragma unroll
    for (int half = 0; half < 2; ++half) {
        float h1[32];
        #pragma unroll
        for (int j = 0; j < 32; ++j) h1[j] = b1[half*32 + j];
        #pragma unroll
        for (int i = 0; i < NODES; ++i) {
            float a = h0[i];
            const float* w1r = W1 + i * NODES + half*32;
            #pragma unroll
            for (int j = 0; j < 32; ++j) h1[j] += a * w1r[j];
        }
        #pragma unroll
        for (int j = 0; j < 32; ++j) { float s = __sinf(h1[j]); out_acc += (0.5f * h1[j] + s * s) * W2[half*32 + j]; }
    }
    out[p] = out_acc;
}

extern "C" void kernel_launch(void* const* d_in, const int* in_sizes, int n_in,
                              void* d_out, int out_size, void* d_ws, size_t ws_size,
                              hipStream_t stream) {
    const float* x      = (const float*)d_in[0];
    const float* gscale = (const float*)d_in[1];
    const float* gtrans = (const float*)d_in[2];
    const float* fg     = (const float*)d_in[3];
    const float* W0     = (const float*)d_in[4];
    const float* b0     = (const float*)d_in[5];
    const float* W1     = (const float*)d_in[6];
    const float* b1     = (const float*)d_in[7];
    const float* W2     = (const float*)d_in[8];
    const float* b2     = (const float*)d_in[9];
    float* out = (float*)d_out;

    // workspace layout:
    //   [0,      24576)  w0t
    //   [24576,  32768)  w1t
    //   [32768,  49152)  hist (4096 int)
    //   [49152,  65536)  offs (4096 int)
    //   [65536,  98304)  masks (4096 uint2)
    //   [1M,     9M)     spts (524288 float4)
    //   [9M,     73M)    vox (packed bf16x2)
    char* wsp = (char*)d_ws;
    unsigned short* w0t = (unsigned short*)wsp;
    unsigned short* w1t = (unsigned short*)(wsp + 24576);
    int* hist           = (int*)(wsp + 32768);
    int* offs           = (int*)(wsp + 49152);
    uint2* masks        = (uint2*)(wsp + 65536);
    float4* spts        = (float4*)(wsp + (1 << 20));
    unsigned int* vox   = (unsigned int*)(wsp + (9 << 20));
    const size_t ws_needed = (size_t)(9 << 20) + (size_t)NG * VOX * 4;

    if (ws_size >= ws_needed) {
        hipMemsetAsync(hist, 0, NCELL * sizeof(int), stream);
        prep_small<<<16 + NCELL / 4 + NPTS / 256, 256, 0, stream>>>(
            W0, W1, gscale, gtrans, x, w0t, w1t, hist, masks);
        sort_scan<<<1, 256, 0, stream>>>(hist, offs);
        prep_big<<<16384 + NPTS / 256, 256, 0, stream>>>(fg, (uint4*)vox, x, offs, spts);
        amrsrn_main<<<NBLK, 256, 0, stream>>>(spts, gscale, gtrans, vox, masks,
                                              w0t, w1t, b0, b1, W2, b2, out);
    } else {
        amrsrn_fallback<<<NPTS / 256, 256, 0, stream>>>(
            x, gscale, gtrans, fg, W0, b0, W1, b1, W2, b2, out);
    }
}